// Round 1
// 2563.354 us; speedup vs baseline: 4.3755x; 4.3755x over previous
//
#include <hip/hip_runtime.h>
#include <stdint.h>

#define TSTEPS 512
#define NB 512
#define ND 512
#define NH 512

#define WPG 32            // counter increments per group per step = 8 WGs * 4 waves
#define NGROUPS 32
#define CTR_STRIDE 64     // uints (256B spacing)

typedef _Float16 half8 __attribute__((ext_vector_type(8)));
typedef float float4v __attribute__((ext_vector_type(4)));

__device__ __forceinline__ float fast_tanh(float x) {
  // tanh(x) = 1 - 2/(e^{2x}+1); saturates correctly at +/-inf, no NaN.
  float e = __expf(2.0f * x);
  return 1.0f - 2.0f * __builtin_amdgcn_rcpf(e + 1.0f);
}

// Persistent RNN kernel. Grid = 256 WGs x 256 threads (4 waves), 1 WG/CU.
// Row-group g = bid&31 owns batch rows [16g,16g+16); col-WG c = bid>>5 owns
// hidden cols [64c, 64c+64). Group members share bid%8 -> same XCD (heuristic).
// Waves K-split (128 K each) over both the D (input) and H (recurrent) dots;
// partials reduced through LDS. W_ih/W_hh slices live entirely in VGPRs as
// pre-built MFMA B-fragments. h ping-pongs through d_ws as fp16.
//
// Sync redesign vs previous version: NO release fence (the old per-wave
// __ATOMIC_RELEASE fetch_add made the compiler emit buffer_wbl2 sc1 -- a full
// dirty-L2 writeback -- 1024x per timestep; that was the dominant per-step
// cost). Instead the h publish itself uses relaxed AGENT-scope (sc1,
// write-through to the LLC coherence point) packed 8B atomic stores, drained
// by an explicit `s_waitcnt vmcnt(0)` (store acks come from the LLC), then a
// RELAXED counter add. Consumer polls relaxed sc1 and reads h relaxed sc1 --
// the whole loop contains zero cache-maintenance instructions.
__global__ void __launch_bounds__(256, 1)
rnn_persistent(const float* __restrict__ x,     // [T,B,D]
               const float* __restrict__ Wih,   // [H,D]
               const float* __restrict__ Whh,   // [H,H]
               const float* __restrict__ bih,   // [H]
               const float* __restrict__ bhh,   // [H]
               float* __restrict__ out,         // [B,H]
               _Float16* __restrict__ hbuf,     // ws: [2][B][H] fp16
               unsigned* __restrict__ counters) // ws: [NGROUPS*CTR_STRIDE]
{
  __shared__ __attribute__((aligned(16))) float red[4][16][68]; // padded rows

  const int bid  = blockIdx.x;
  const int grp  = bid & 31;
  const int cwg  = bid >> 5;              // 0..7
  const int wave = threadIdx.x >> 6;      // 0..3
  const int lane = threadIdx.x & 63;
  const int m    = lane & 15;
  const int quad = lane >> 4;
  const int tid  = threadIdx.x;

  const int R     = grp * 16;             // batch-row base
  const int C0    = cwg * 64;             // hidden-col base
  const int kbase = wave * 128;           // this wave's K slice

  unsigned* ctr = counters + grp * CTR_STRIDE;

  // ---- preload W fragments (MFMA B-operand layout) into registers ----
  // B[k][n], n = lane&15 (+tile*16), k = quad*8 + j (+kk*32 + kbase)
  half8 wih_f[4][4];  // [kk][tile]
  half8 whh_f[4][4];
  #pragma unroll
  for (int tile = 0; tile < 4; ++tile) {
    const int n = C0 + tile * 16 + m;
    const float* wr_ih = Wih + (size_t)n * ND;
    const float* wr_hh = Whh + (size_t)n * NH;
    #pragma unroll
    for (int kk = 0; kk < 4; ++kk) {
      const int k0 = kbase + kk * 32 + quad * 8;
      half8 a, b;
      #pragma unroll
      for (int j = 0; j < 8; ++j) {
        a[j] = (_Float16)wr_ih[k0 + j];   // RTNE cast: rel err 2^-11
        b[j] = (_Float16)wr_hh[k0 + j];
      }
      wih_f[kk][tile] = a;
      whh_f[kk][tile] = b;
    }
  }

  // Publish-side assignment: thread tid owns (row R+prow, cols C0+pcol..+3)
  // -> one packed 8B fp16 store (4 x 128B segments per wave, coalesced).
  const int prow = tid >> 4;              // 0..15
  const int pcol = (tid & 15) * 4;        // 0..60
  float4v bias4;
  #pragma unroll
  for (int j = 0; j < 4; ++j)
    bias4[j] = bih[C0 + pcol + j] + bhh[C0 + pcol + j];

  const int myrow = R + m;                // A-operand row (m = lane&15)
  const int orow  = quad * 4;             // C/D row base (row = quad*4 + reg)

  for (int t = 0; t < TSTEPS; ++t) {
    float4v acc[4];
    #pragma unroll
    for (int tile = 0; tile < 4; ++tile) acc[tile] = (float4v){0.f, 0.f, 0.f, 0.f};

    // ---- x-part: on-the-fly input projection (overlaps peers' publish) ----
    const float* xrow = x + ((size_t)t * NB + myrow) * ND + kbase + quad * 8;
    float4v xv[4][2];
    #pragma unroll
    for (int kk = 0; kk < 4; ++kk) {
      xv[kk][0] = *(const float4v*)(xrow + kk * 32);
      xv[kk][1] = *(const float4v*)(xrow + kk * 32 + 4);
    }
    #pragma unroll
    for (int kk = 0; kk < 4; ++kk) {
      half8 a;
      #pragma unroll
      for (int j = 0; j < 4; ++j) {
        a[j]     = (_Float16)xv[kk][0][j];
        a[j + 4] = (_Float16)xv[kk][1][j];
      }
      #pragma unroll
      for (int tile = 0; tile < 4; ++tile)
        acc[tile] = __builtin_amdgcn_mfma_f32_16x16x32_f16(a, wih_f[kk][tile], acc[tile], 0, 0, 0);
    }

    // ---- wait for h_t (all 32 waves of the group published), then h-part ----
    if (t > 0) {
      const unsigned tgt = (unsigned)(WPG * t);
      unsigned c;
      while ((c = __hip_atomic_load(ctr, __ATOMIC_RELAXED, __HIP_MEMORY_SCOPE_AGENT)) < tgt)
        __builtin_amdgcn_s_sleep(1);
      // (c >> 31) == 0 at runtime (counter < 2^31) but opaque to the compiler:
      // forces the h loads to be data-dependent on the successful poll so they
      // cannot be hoisted above it. Producer stores were sc1 (acked by the
      // LLC) and drained by vmcnt(0) before the counter bump, so sc1 relaxed
      // loads here observe them at the coherence point.
      const _Float16* hb = hbuf + (size_t)(t & 1) * NB * NH + (size_t)(c >> 31);
      const unsigned long long* hrow =
          (const unsigned long long*)(hb + (size_t)myrow * NH + kbase + quad * 8);
      #pragma unroll
      for (int kk = 0; kk < 4; ++kk) {
        unsigned long long lo = __hip_atomic_load(hrow + kk * 8,     __ATOMIC_RELAXED, __HIP_MEMORY_SCOPE_AGENT);
        unsigned long long hi = __hip_atomic_load(hrow + kk * 8 + 1, __ATOMIC_RELAXED, __HIP_MEMORY_SCOPE_AGENT);
        union { unsigned long long u[2]; half8 h; } cv;
        cv.u[0] = lo; cv.u[1] = hi;
        #pragma unroll
        for (int tile = 0; tile < 4; ++tile)
          acc[tile] = __builtin_amdgcn_mfma_f32_16x16x32_f16(cv.h, whh_f[kk][tile], acc[tile], 0, 0, 0);
      }
    }

    // ---- cross-wave K reduction via LDS ----
    #pragma unroll
    for (int tile = 0; tile < 4; ++tile) {
      #pragma unroll
      for (int r = 0; r < 4; ++r)
        red[wave][orow + r][tile * 16 + m] = acc[tile][r];
    }
    __syncthreads();
    // (write(t+1) vs read(t) hazard is covered by the group counter: a wave
    //  cannot pass poll(32*(t+1)) until every group wave bumped ctr for t, and
    //  each wave's bump is program-ordered after its LDS reads below.)
    float4v s = bias4;
    #pragma unroll
    for (int w = 0; w < 4; ++w) {
      const float4v v = *(const float4v*)&red[w][prow][pcol];
      s[0] += v[0]; s[1] += v[1]; s[2] += v[2]; s[3] += v[3];
    }
    float4v o;
    #pragma unroll
    for (int j = 0; j < 4; ++j) o[j] = fast_tanh(s[j]);

    // ---- publish h_{t+1} (packed 8B, sc1 write-through) or final output ----
    if (t < TSTEPS - 1) {
      _Float16* hb1 = hbuf + (size_t)((t + 1) & 1) * NB * NH;
      union { _Float16 h[4]; unsigned long long u; } pk;
      #pragma unroll
      for (int j = 0; j < 4; ++j) pk.h[j] = (_Float16)o[j];
      __hip_atomic_store(
          (unsigned long long*)(hb1 + (size_t)(R + prow) * NH + C0 + pcol),
          pk.u, __ATOMIC_RELAXED, __HIP_MEMORY_SCOPE_AGENT);
      // Hand-rolled release: all stores above are agent-scope (sc1), so their
      // vmcnt acks come from the LLC (the agent coherence point). Draining
      // them is a complete release -- no buffer_wbl2 needed.
      asm volatile("s_waitcnt vmcnt(0)" ::: "memory");
      if (lane == 0)
        __hip_atomic_fetch_add(ctr, 1u, __ATOMIC_RELAXED, __HIP_MEMORY_SCOPE_AGENT);
    } else {
      *(float4v*)(out + (size_t)(R + prow) * NH + C0 + pcol) = o;
    }
  }
}

extern "C" void kernel_launch(void* const* d_in, const int* in_sizes, int n_in,
                              void* d_out, int out_size, void* d_ws, size_t ws_size,
                              hipStream_t stream) {
  const float* x   = (const float*)d_in[0];
  const float* Wih = (const float*)d_in[1];
  const float* Whh = (const float*)d_in[2];
  const float* bih = (const float*)d_in[3];
  const float* bhh = (const float*)d_in[4];
  // d_in[5] = hidden_size scalar (unused; H fixed at 512)
  float* out = (float*)d_out;

  _Float16* hbuf     = (_Float16*)d_ws;                                  // 1 MB
  unsigned* counters = (unsigned*)((char*)d_ws + (size_t)2 * NB * NH * 2);

  (void)hipMemsetAsync(counters, 0, NGROUPS * CTR_STRIDE * sizeof(unsigned), stream);

  rnn_persistent<<<dim3(256), dim3(256), 0, stream>>>(
      x, Wih, Whh, bih, bhh, out, hbuf, counters);
}

// Round 2
// 2193.009 us; speedup vs baseline: 5.1144x; 1.1689x over previous
//
#include <hip/hip_runtime.h>
#include <stdint.h>

#define TSTEPS 512
#define NB 512
#define ND 512
#define NH 512

#define NGROUPS 32
#define CELL_STRIDE 64    // uints (256B spacing between flag cells)

typedef _Float16 half8 __attribute__((ext_vector_type(8)));
typedef float float4v __attribute__((ext_vector_type(4)));

__device__ __forceinline__ float fast_tanh(float x) {
  // tanh(x) = 1 - 2/(e^{2x}+1); saturates correctly at +/-inf, no NaN.
  float e = __expf(2.0f * x);
  return 1.0f - 2.0f * __builtin_amdgcn_rcpf(e + 1.0f);
}

// Persistent RNN kernel. Grid = 256 WGs x 256 threads (4 waves), 1 WG/CU.
// Row-group g = bid&31 owns batch rows [16g,16g+16); col-WG c = bid>>5 owns
// hidden cols [64c, 64c+64). Group members share bid%8 -> same XCD (heuristic).
// Waves K-split (128 K each); partials reduced through LDS. W slices live in
// VGPRs as MFMA B-fragments. h ping-pongs through d_ws as fp16.
//
// R2 sync redesign: the old single group counter took 32 serialized
// same-address agent RMWs per step (the poll target = the LAST of them).
// Now each WG has its OWN flag cell (256B apart): per-wave vmcnt(0) drain ->
// __syncthreads -> ONE plain sc1 store of (t+1). 8 independent one-way
// stores commit in parallel. Consumer wave w polls only the 2 cells (2w,2w+1)
// that produce its K-slice columns. The red[] write(t+1)/read(t) hazard the
// counter used to cover is now covered by barrier #2 (all local LDS reads
// precede it).
// R2 latency fix: x_t loads were issued after the t-1 publish and exposed
// ~900cy of HBM latency per step. Now x_{t+1} is prefetched (double-buffered
// registers, unroll-by-2 with named buffers) right after the x-MFMA of step t,
// hiding HBM under the poll/h-load/publish window.
__global__ void __launch_bounds__(256, 1)
rnn_persistent(const float* __restrict__ x,     // [T,B,D]
               const float* __restrict__ Wih,   // [H,D]
               const float* __restrict__ Whh,   // [H,H]
               const float* __restrict__ bih,   // [H]
               const float* __restrict__ bhh,   // [H]
               float* __restrict__ out,         // [B,H]
               _Float16* __restrict__ hbuf,     // ws: [2][B][H] fp16
               unsigned* __restrict__ flags)    // ws: [NGROUPS][8][CELL_STRIDE]
{
  __shared__ __attribute__((aligned(16))) float red[4][16][68]; // padded rows

  const int bid  = blockIdx.x;
  const int grp  = bid & 31;
  const int cwg  = bid >> 5;              // 0..7
  const int wave = threadIdx.x >> 6;      // 0..3
  const int lane = threadIdx.x & 63;
  const int m    = lane & 15;
  const int quad = lane >> 4;
  const int tid  = threadIdx.x;

  const int R     = grp * 16;             // batch-row base
  const int C0    = cwg * 64;             // hidden-col base
  const int kbase = wave * 128;           // this wave's K slice

  unsigned* gflags = flags + (size_t)grp * 8 * CELL_STRIDE;
  unsigned* myflag = gflags + cwg * CELL_STRIDE;
  // wave w's K-slice cols [128w,128w+128) are produced by WGs 2w and 2w+1.
  const unsigned* pollcell = gflags + ((wave << 1) | (lane & 1)) * CELL_STRIDE;

  // ---- preload W fragments (MFMA B-operand layout) into registers ----
  // B[k][n], n = lane&15 (+tile*16), k = quad*8 + j (+kk*32 + kbase)
  half8 wih_f[4][4];  // [kk][tile]
  half8 whh_f[4][4];
  #pragma unroll
  for (int tile = 0; tile < 4; ++tile) {
    const int n = C0 + tile * 16 + m;
    const float* wr_ih = Wih + (size_t)n * ND;
    const float* wr_hh = Whh + (size_t)n * NH;
    #pragma unroll
    for (int kk = 0; kk < 4; ++kk) {
      const int k0 = kbase + kk * 32 + quad * 8;
      half8 a, b;
      #pragma unroll
      for (int j = 0; j < 8; ++j) {
        a[j] = (_Float16)wr_ih[k0 + j];   // RTNE cast: rel err 2^-11
        b[j] = (_Float16)wr_hh[k0 + j];
      }
      wih_f[kk][tile] = a;
      whh_f[kk][tile] = b;
    }
  }

  // Publish-side assignment: thread tid owns (row R+prow, cols C0+pcol..+3)
  // -> one packed 8B fp16 store (4 x 128B segments per wave, coalesced).
  const int prow = tid >> 4;              // 0..15
  const int pcol = (tid & 15) * 4;        // 0..60
  float4v bias4;
  #pragma unroll
  for (int j = 0; j < 4; ++j)
    bias4[j] = bih[C0 + pcol + j] + bhh[C0 + pcol + j];

  const int myrow = R + m;                // A-operand row (m = lane&15)
  const int orow  = quad * 4;             // C/D row base (row = quad*4 + reg)

  // ---- x double-buffer: preload t=0 ----
  float4v xvA[4][2], xvB[4][2];
  {
    const float* xrow0 = x + (size_t)myrow * ND + kbase + quad * 8;
    #pragma unroll
    for (int kk = 0; kk < 4; ++kk) {
      xvA[kk][0] = *(const float4v*)(xrow0 + kk * 32);
      xvA[kk][1] = *(const float4v*)(xrow0 + kk * 32 + 4);
    }
  }

#define STEP(T, XU, XP)                                                        \
  {                                                                            \
    const int t_ = (T);                                                        \
    float4v acc[4];                                                            \
    _Pragma("unroll")                                                          \
    for (int tile = 0; tile < 4; ++tile) acc[tile] = (float4v){0.f,0.f,0.f,0.f};\
    /* x-part: uses prefetched registers (no memory wait) */                   \
    _Pragma("unroll")                                                          \
    for (int kk = 0; kk < 4; ++kk) {                                           \
      half8 a;                                                                 \
      _Pragma("unroll")                                                        \
      for (int j = 0; j < 4; ++j) {                                            \
        a[j]     = (_Float16)XU[kk][0][j];                                     \
        a[j + 4] = (_Float16)XU[kk][1][j];                                     \
      }                                                                        \
      _Pragma("unroll")                                                        \
      for (int tile = 0; tile < 4; ++tile)                                     \
        acc[tile] = __builtin_amdgcn_mfma_f32_16x16x32_f16(a, wih_f[kk][tile], acc[tile], 0, 0, 0); \
    }                                                                          \
    /* prefetch x for t+1 into the dead buffer; overlaps poll+h+publish */     \
    {                                                                          \
      const int tn_ = (t_ + 1 < TSTEPS) ? (t_ + 1) : t_;                       \
      const float* xrow_ = x + ((size_t)tn_ * NB + myrow) * ND + kbase + quad * 8; \
      _Pragma("unroll")                                                        \
      for (int kk = 0; kk < 4; ++kk) {                                         \
        XP[kk][0] = *(const float4v*)(xrow_ + kk * 32);                        \
        XP[kk][1] = *(const float4v*)(xrow_ + kk * 32 + 4);                    \
      }                                                                        \
    }                                                                          \
    /* wait for the 2 producer WGs of this wave's K-slice, then h-part */      \
    if (t_ > 0) {                                                              \
      const unsigned tgt = (unsigned)t_;                                       \
      unsigned v;                                                              \
      for (;;) {                                                               \
        v = __hip_atomic_load(pollcell, __ATOMIC_RELAXED, __HIP_MEMORY_SCOPE_AGENT); \
        if (__all((int)(v >= tgt))) break;                                     \
        __builtin_amdgcn_s_sleep(1);                                           \
      }                                                                        \
      /* data-dep trick: h addrs depend on BOTH polled cells (own + partner    \
         lane's via shfl); (v|v2)>>31 == 0 at runtime, opaque to compiler. */  \
      const unsigned v2 = (unsigned)__shfl_xor((int)v, 1, 64);                 \
      const _Float16* hb = hbuf + (size_t)(t_ & 1) * NB * NH + (size_t)((v | v2) >> 31); \
      const unsigned long long* hrow =                                         \
          (const unsigned long long*)(hb + (size_t)myrow * NH + kbase + quad * 8); \
      _Pragma("unroll")                                                        \
      for (int kk = 0; kk < 4; ++kk) {                                         \
        unsigned long long lo = __hip_atomic_load(hrow + kk * 8,     __ATOMIC_RELAXED, __HIP_MEMORY_SCOPE_AGENT); \
        unsigned long long hi = __hip_atomic_load(hrow + kk * 8 + 1, __ATOMIC_RELAXED, __HIP_MEMORY_SCOPE_AGENT); \
        union { unsigned long long u[2]; half8 h; } cv;                        \
        cv.u[0] = lo; cv.u[1] = hi;                                            \
        _Pragma("unroll")                                                      \
        for (int tile = 0; tile < 4; ++tile)                                   \
          acc[tile] = __builtin_amdgcn_mfma_f32_16x16x32_f16(cv.h, whh_f[kk][tile], acc[tile], 0, 0, 0); \
      }                                                                        \
    }                                                                          \
    /* cross-wave K reduction via LDS */                                       \
    _Pragma("unroll")                                                          \
    for (int tile = 0; tile < 4; ++tile) {                                     \
      _Pragma("unroll")                                                        \
      for (int r = 0; r < 4; ++r)                                              \
        red[wave][orow + r][tile * 16 + m] = acc[tile][r];                     \
    }                                                                          \
    __syncthreads(); /* barrier #1 */                                          \
    float4v s = bias4;                                                         \
    _Pragma("unroll")                                                          \
    for (int w = 0; w < 4; ++w) {                                              \
      const float4v vv = *(const float4v*)&red[w][prow][pcol];                 \
      s[0] += vv[0]; s[1] += vv[1]; s[2] += vv[2]; s[3] += vv[3];              \
    }                                                                          \
    float4v o;                                                                 \
    _Pragma("unroll")                                                          \
    for (int j = 0; j < 4; ++j) o[j] = fast_tanh(s[j]);                        \
    if (t_ < TSTEPS - 1) {                                                     \
      _Float16* hb1 = hbuf + (size_t)((t_ + 1) & 1) * NB * NH;                 \
      union { _Float16 h[4]; unsigned long long u; } pk;                       \
      _Pragma("unroll")                                                        \
      for (int j = 0; j < 4; ++j) pk.h[j] = (_Float16)o[j];                    \
      __hip_atomic_store(                                                      \
          (unsigned long long*)(hb1 + (size_t)(R + prow) * NH + C0 + pcol),    \
          pk.u, __ATOMIC_RELAXED, __HIP_MEMORY_SCOPE_AGENT);                   \
      /* hand-rolled release: sc1 stores ack from the LLC; draining them IS    \
         the release. (Also waits the x prefetch -- usually already done.) */  \
      asm volatile("s_waitcnt vmcnt(0)" ::: "memory");                         \
      __syncthreads(); /* barrier #2: all local waves drained + red[] read */  \
      if (tid == 0)                                                            \
        __hip_atomic_store(myflag, (unsigned)(t_ + 1), __ATOMIC_RELAXED, __HIP_MEMORY_SCOPE_AGENT); \
    } else {                                                                   \
      *(float4v*)(out + (size_t)(R + prow) * NH + C0 + pcol) = o;              \
    }                                                                          \
  }

  for (int t = 0; t < TSTEPS; t += 2) {
    STEP(t,     xvA, xvB);
    STEP(t + 1, xvB, xvA);
  }
#undef STEP
}

extern "C" void kernel_launch(void* const* d_in, const int* in_sizes, int n_in,
                              void* d_out, int out_size, void* d_ws, size_t ws_size,
                              hipStream_t stream) {
  const float* x   = (const float*)d_in[0];
  const float* Wih = (const float*)d_in[1];
  const float* Whh = (const float*)d_in[2];
  const float* bih = (const float*)d_in[3];
  const float* bhh = (const float*)d_in[4];
  // d_in[5] = hidden_size scalar (unused; H fixed at 512)
  float* out = (float*)d_out;

  _Float16* hbuf  = (_Float16*)d_ws;                                   // 1 MB
  unsigned* flags = (unsigned*)((char*)d_ws + (size_t)2 * NB * NH * 2);

  (void)hipMemsetAsync(flags, 0,
                       (size_t)NGROUPS * 8 * CELL_STRIDE * sizeof(unsigned),
                       stream);

  rnn_persistent<<<dim3(256), dim3(256), 0, stream>>>(
      x, Wih, Whh, bih, bhh, out, hbuf, flags);
}

// Round 4
// 2149.109 us; speedup vs baseline: 5.2189x; 1.0204x over previous
//
#include <hip/hip_runtime.h>
#include <stdint.h>

#define TSTEPS 512
#define NB 512
#define ND 512
#define NH 512
#define SENT 0xFFFFFFFFFFFFFFFFull

typedef _Float16 half8 __attribute__((ext_vector_type(8)));
typedef float float4v __attribute__((ext_vector_type(4)));
typedef unsigned long long u64;

__device__ __forceinline__ float fast_tanh(float x) {
  // tanh(x) = 1 - 2/(e^{2x}+1); saturates correctly at +/-inf, no NaN.
  float e = __expf(2.0f * x);
  return 1.0f - 2.0f * __builtin_amdgcn_rcpf(e + 1.0f);
}

// Agent-scope (sc1, served at the device coherence point) relaxed ops.
// This is the ONE scope proven correct on this HW by R1/R2 runs.
#define AL(p)    __hip_atomic_load((p), __ATOMIC_RELAXED, __HIP_MEMORY_SCOPE_AGENT)
#define AS(p, v) __hip_atomic_store((p), (v), __ATOMIC_RELAXED, __HIP_MEMORY_SCOPE_AGENT)

// LDS-only barrier: waits ds ops (lgkmcnt) then s_barrier, WITHOUT the
// vmcnt(0) drain __syncthreads adds (which would stall on the in-flight
// x-prefetch / publish stores).
#define LDSBAR()                                                               \
  do {                                                                         \
    asm volatile("s_waitcnt lgkmcnt(0)" ::: "memory");                         \
    __builtin_amdgcn_s_barrier();                                              \
  } while (0)

#define PREFETCH_X(XP, TN)                                                     \
  do {                                                                         \
    const float* xrow_ = x + ((size_t)(TN) * NB + myrow) * ND + kbase + quad * 8; \
    _Pragma("unroll")                                                          \
    for (int kk = 0; kk < 4; ++kk) {                                           \
      XP[kk][0] = *(const float4v*)(xrow_ + kk * 32);                          \
      XP[kk][1] = *(const float4v*)(xrow_ + kk * 32 + 4);                      \
    }                                                                          \
  } while (0)

// Persistent RNN. Grid = 256 WGs x 256 threads, 1 WG/CU. Group g=bid&31 owns
// batch rows [16g,16g+16); col-WG c=bid>>5 owns cols [64c,64c+64). Groups are
// fully independent 8-WG rings. Waves K-split (128 K each); cross-wave K
// reduction via LDS (double-buffered by step parity -> ONE barrier per step);
// W fragments live in VGPRs. h ring of 4 fp16 buffers in d_ws.
//
// R4 exchange: flagless sentinel at AGENT scope (sc1) only.
//  * Ring pre-filled with 0xFFFF (fp16 NaN; tanh output can never encode it).
//    Each 8B word is written by exactly ONE thread -> word-granular
//    validation is tear-free. Consumers retry-load until all 8 words of
//    their slice != sentinel: the validating load IS the data load (no
//    producer drain, no flag store, no separate poll round-trip).
//  * WAR: WG clears its own region of buf[(t+2)&3] at the TOP of step t.
//    Validating h(t-1) proved every producer thread published h(t-1), which
//    is after its step-(t-2) barrier, which is after its reads of that
//    buffer. So no in-flight reader exists.
//  * ABA: the vmcnt(0) right before the publish retires the clear to the
//    LLC BEFORE h(t+1) becomes visible. A consumer reaches the h(t+2)
//    validation only after observing h(t+1), hence it can only see
//    sentinel-or-h(t+2) in the cleared buffer, never stale h(t-2).
__global__ void __launch_bounds__(256, 1)
rnn_persistent(const float* __restrict__ x,     // [T,B,D]
               const float* __restrict__ Wih,   // [H,D]
               const float* __restrict__ Whh,   // [H,H]
               const float* __restrict__ bih,   // [H]
               const float* __restrict__ bhh,   // [H]
               float* __restrict__ out,         // [B,H]
               _Float16* __restrict__ hbuf)     // ws: [4][B][H] fp16 ring
{
  __shared__ __attribute__((aligned(16))) float red[2][4][16][68]; // dbuf

  const int bid  = blockIdx.x;
  const int grp  = bid & 31;
  const int cwg  = bid >> 5;              // 0..7
  const int wave = threadIdx.x >> 6;      // 0..3
  const int lane = threadIdx.x & 63;
  const int m    = lane & 15;
  const int quad = lane >> 4;
  const int tid  = threadIdx.x;

  const int R     = grp * 16;             // batch-row base
  const int C0    = cwg * 64;             // hidden-col base
  const int kbase = wave * 128;           // this wave's K slice

  // ---- preload W fragments (MFMA B-operand layout) into registers ----
  // B[k][n], n = lane&15 (+tile*16), k = quad*8 + j (+kk*32 + kbase)
  half8 wih_f[4][4];  // [kk][tile]
  half8 whh_f[4][4];
  #pragma unroll
  for (int tile = 0; tile < 4; ++tile) {
    const int n = C0 + tile * 16 + m;
    const float* wr_ih = Wih + (size_t)n * ND;
    const float* wr_hh = Whh + (size_t)n * NH;
    #pragma unroll
    for (int kk = 0; kk < 4; ++kk) {
      const int k0 = kbase + kk * 32 + quad * 8;
      half8 a, b;
      #pragma unroll
      for (int j = 0; j < 8; ++j) {
        a[j] = (_Float16)wr_ih[k0 + j];   // RTNE cast: rel err 2^-11
        b[j] = (_Float16)wr_hh[k0 + j];
      }
      wih_f[kk][tile] = a;
      whh_f[kk][tile] = b;
    }
  }

  // Publish-side assignment: thread tid owns (row R+prow, cols C0+pcol..+3)
  // -> one packed 8B fp16 store per step; unique writer per 8B word.
  const int prow = tid >> 4;              // 0..15
  const int pcol = (tid & 15) * 4;        // 0..60
  float4v bias4;
  #pragma unroll
  for (int j = 0; j < 4; ++j)
    bias4[j] = bih[C0 + pcol + j] + bhh[C0 + pcol + j];

  const int myrow = R + m;                // A-operand row
  const int orow  = quad * 4;             // C/D row base

  // ---- x double-buffer: preload t=0 ----
  float4v xvA[4][2], xvB[4][2];
  {
    const float* xrow0 = x + (size_t)myrow * ND + kbase + quad * 8;
    #pragma unroll
    for (int kk = 0; kk < 4; ++kk) {
      xvA[kk][0] = *(const float4v*)(xrow0 + kk * 32);
      xvA[kk][1] = *(const float4v*)(xrow0 + kk * 32 + 4);
    }
  }

#define STEP(T, PAR, XU, XP)                                                   \
  {                                                                            \
    const int t_ = (T);                                                        \
    /* WAR-safe clear of the ring slot rewritten at the end of step t_+1 */    \
    if (t_ >= 2) {                                                             \
      u64* cl = (u64*)(hbuf + (size_t)((t_ + 2) & 3) * NB * NH +               \
                       (size_t)(R + prow) * NH + C0 + pcol);                   \
      AS(cl, SENT);                                                            \
    }                                                                          \
    float4v acc[4];                                                            \
    _Pragma("unroll")                                                          \
    for (int tile = 0; tile < 4; ++tile) acc[tile] = (float4v){0.f,0.f,0.f,0.f};\
    /* x-part from prefetched registers */                                     \
    _Pragma("unroll")                                                          \
    for (int kk = 0; kk < 4; ++kk) {                                           \
      half8 a;                                                                 \
      _Pragma("unroll")                                                        \
      for (int j = 0; j < 4; ++j) {                                            \
        a[j]     = (_Float16)XU[kk][0][j];                                     \
        a[j + 4] = (_Float16)XU[kk][1][j];                                     \
      }                                                                        \
      _Pragma("unroll")                                                        \
      for (int tile = 0; tile < 4; ++tile)                                     \
        acc[tile] = __builtin_amdgcn_mfma_f32_16x16x32_f16(a, wih_f[kk][tile], acc[tile], 0, 0, 0); \
    }                                                                          \
    if (t_ > 0) {                                                              \
      const int tn_ = (t_ + 1 < TSTEPS) ? (t_ + 1) : t_;                       \
      const _Float16* hb = hbuf + (size_t)(t_ & 3) * NB * NH;                  \
      const u64* hrow = (const u64*)(hb + (size_t)myrow * NH + kbase + quad * 8); \
      /* issue the 8 h-loads, then the x-prefetch: h are OLDEST in the vmcnt  \
         FIFO, so the compiler's wait for the validity check is vmcnt(8) and  \
         the x stream stays in flight. */                                     \
      u64 w0 = AL(hrow + 0), w1 = AL(hrow + 1);                                \
      u64 w2 = AL(hrow + 8), w3 = AL(hrow + 9);                                \
      u64 w4 = AL(hrow + 16), w5 = AL(hrow + 17);                              \
      u64 w6 = AL(hrow + 24), w7 = AL(hrow + 25);                              \
      PREFETCH_X(XP, tn_);                                                     \
      for (;;) {                                                               \
        bool ok = (w0 != SENT) & (w1 != SENT) & (w2 != SENT) & (w3 != SENT) &  \
                  (w4 != SENT) & (w5 != SENT) & (w6 != SENT) & (w7 != SENT);   \
        if (__all((int)ok)) break;                                             \
        __builtin_amdgcn_s_sleep(1);   /* throttle LLC retry traffic */        \
        w0 = AL(hrow + 0); w1 = AL(hrow + 1);                                  \
        w2 = AL(hrow + 8); w3 = AL(hrow + 9);                                  \
        w4 = AL(hrow + 16); w5 = AL(hrow + 17);                                \
        w6 = AL(hrow + 24); w7 = AL(hrow + 25);                                \
      }                                                                        \
      union { u64 u[2]; half8 h; } cvv;                                        \
      cvv.u[0] = w0; cvv.u[1] = w1;                                            \
      _Pragma("unroll")                                                        \
      for (int tile = 0; tile < 4; ++tile)                                     \
        acc[tile] = __builtin_amdgcn_mfma_f32_16x16x32_f16(cvv.h, whh_f[0][tile], acc[tile], 0, 0, 0); \
      cvv.u[0] = w2; cvv.u[1] = w3;                                            \
      _Pragma("unroll")                                                        \
      for (int tile = 0; tile < 4; ++tile)                                     \
        acc[tile] = __builtin_amdgcn_mfma_f32_16x16x32_f16(cvv.h, whh_f[1][tile], acc[tile], 0, 0, 0); \
      cvv.u[0] = w4; cvv.u[1] = w5;                                            \
      _Pragma("unroll")                                                        \
      for (int tile = 0; tile < 4; ++tile)                                     \
        acc[tile] = __builtin_amdgcn_mfma_f32_16x16x32_f16(cvv.h, whh_f[2][tile], acc[tile], 0, 0, 0); \
      cvv.u[0] = w6; cvv.u[1] = w7;                                            \
      _Pragma("unroll")                                                        \
      for (int tile = 0; tile < 4; ++tile)                                     \
        acc[tile] = __builtin_amdgcn_mfma_f32_16x16x32_f16(cvv.h, whh_f[3][tile], acc[tile], 0, 0, 0); \
    } else {                                                                   \
      PREFETCH_X(XP, 1);                                                       \
    }                                                                          \
    /* cross-wave K reduction via LDS (parity buffer PAR) */                   \
    _Pragma("unroll")                                                          \
    for (int tile = 0; tile < 4; ++tile) {                                     \
      _Pragma("unroll")                                                        \
      for (int r = 0; r < 4; ++r)                                              \
        red[PAR][wave][orow + r][tile * 16 + m] = acc[tile][r];                \
    }                                                                          \
    LDSBAR(); /* single barrier per step; parity dbuf covers reuse hazard */   \
    float4v s = bias4;                                                         \
    _Pragma("unroll")                                                          \
    for (int w = 0; w < 4; ++w) {                                              \
      const float4v vv = *(const float4v*)&red[PAR][w][prow][pcol];            \
      s[0] += vv[0]; s[1] += vv[1]; s[2] += vv[2]; s[3] += vv[3];              \
    }                                                                          \
    float4v o;                                                                 \
    _Pragma("unroll")                                                          \
    for (int j = 0; j < 4; ++j) o[j] = fast_tanh(s[j]);                        \
    if (t_ < TSTEPS - 1) {                                                     \
      u64* dst = (u64*)(hbuf + (size_t)((t_ + 1) & 3) * NB * NH +              \
                        (size_t)(R + prow) * NH + C0 + pcol);                  \
      union { _Float16 h[4]; u64 u; } pk;                                      \
      _Pragma("unroll")                                                        \
      for (int j = 0; j < 4; ++j) pk.h[j] = (_Float16)o[j];                    \
      /* retire the step-top clear (and everything older) BEFORE the publish  \
         becomes visible -- this is the ABA guard. Near-free: clear/h/x ops   \
         were issued >1000cy ago. */                                          \
      asm volatile("s_waitcnt vmcnt(0)" ::: "memory");                         \
      AS(dst, pk.u);                                                           \
    } else {                                                                   \
      *(float4v*)(out + (size_t)(R + prow) * NH + C0 + pcol) = o;              \
    }                                                                          \
  }

  for (int t = 0; t < TSTEPS; t += 2) {
    STEP(t,     0, xvA, xvB);
    STEP(t + 1, 1, xvB, xvA);
  }
#undef STEP
}

extern "C" void kernel_launch(void* const* d_in, const int* in_sizes, int n_in,
                              void* d_out, int out_size, void* d_ws, size_t ws_size,
                              hipStream_t stream) {
  const float* x   = (const float*)d_in[0];
  const float* Wih = (const float*)d_in[1];
  const float* Whh = (const float*)d_in[2];
  const float* bih = (const float*)d_in[3];
  const float* bhh = (const float*)d_in[4];
  // d_in[5] = hidden_size scalar (unused; H fixed at 512)
  float* out = (float*)d_out;

  _Float16* hbuf = (_Float16*)d_ws;       // ring: 4 x [B][H] fp16 = 2 MB

  // Pre-fill the ring with the sentinel (0xFFFF = fp16 NaN) each launch
  // (graph-capture safe: async memset on the stream).
  (void)hipMemsetAsync(hbuf, 0xFF, (size_t)4 * NB * NH * sizeof(_Float16), stream);

  rnn_persistent<<<dim3(256), dim3(256), 0, stream>>>(
      x, Wih, Whh, bih, bhh, out, hbuf);
}